// Round 7
// baseline (280.737 us; speedup 1.0000x reference)
//
#include <hip/hip_runtime.h>

// EnvironmentalAugmentations: pink = AR(1) scan of white noise (a=0.99, b=0.01),
// mixed = waveform + 0.05*pink, out = mixed / max(|mixed|) if max > 1 else mixed.
// Shapes: (256 channels, 220500 samples), f32 in / f32 out.
//
// R1 175us / R3 173us / R4 170us / R5 170us / R6 170us: all intra-block latency
// tricks failed; waves have ~30% load-outstanding duty cycle (burst, then long
// scan/barrier/epilogue with nothing in flight).
// R7: persistent blocks, 9 chunks each (grid 3x256). Software pipeline ACROSS
// chunks: issue chunk j+1's loads into alternate register buffer BEFORE
// computing chunk j (explicit A/B buffers, fully unrolled -> compile-time
// indexing). Memory stays busy through the compute phases. Chunks within a
// block chain the exact AR(1) exit state -> warm-up only at block starts.

#define TLEN 220500
#define CHANNELS 256

constexpr int CL   = 8192;          // samples per chunk
constexpr int NT   = 256;           // threads per block
constexpr int NSB  = 8;             // superblocks per chunk (1024 samples each)
constexpr int NCHUNK = 27;          // chunks per channel (27*8192 >= 220500)
constexpr int CPB  = 9;             // chunks per block
constexpr int BPC  = NCHUNK / CPB;  // 3 blocks per channel
constexpr int NBLK = BPC * CHANNELS;// 768 pink_mix blocks

constexpr float AC = 0.99f;
constexpr float BC = 0.01f;
constexpr float NL = 0.05f;

constexpr double dpow(double a, int n) { double r = 1.0; for (int i = 0; i < n; ++i) r *= a; return r; }

// Geometric Hillis-Steele step multipliers, 4-sample granularity: 0.99^(4d)
constexpr float WP0 = (float)dpow(0.99, 4 * 1);
constexpr float WP1 = (float)dpow(0.99, 4 * 2);
constexpr float WP2 = (float)dpow(0.99, 4 * 4);
constexpr float WP3 = (float)dpow(0.99, 4 * 8);
constexpr float WP4 = (float)dpow(0.99, 4 * 16);
constexpr float WP5 = (float)dpow(0.99, 4 * 32);
constexpr float A256  = (float)dpow(0.99, 256);    // wave span (64 lanes x 4)
constexpr float A1024 = (float)dpow(0.99, 1024);   // superblock span
constexpr float L2A4   = -0.05799827878044602f;    // 4   * log2(0.99)
constexpr float L2A256 = -3.7118898419485456f;     // 256 * log2(0.99)

__global__ void init_max_kernel(unsigned int* gmax) { *gmax = 0u; }

__device__ __forceinline__ float wave_scan4(float f, int lane) {
    // inclusive geometric scan across 64 lanes, 4 samples per lane
    { float o = __shfl_up(f, 1,  64); if (lane >= 1)  f = fmaf(WP0, o, f); }
    { float o = __shfl_up(f, 2,  64); if (lane >= 2)  f = fmaf(WP1, o, f); }
    { float o = __shfl_up(f, 4,  64); if (lane >= 4)  f = fmaf(WP2, o, f); }
    { float o = __shfl_up(f, 8,  64); if (lane >= 8)  f = fmaf(WP3, o, f); }
    { float o = __shfl_up(f, 16, 64); if (lane >= 16) f = fmaf(WP4, o, f); }
    { float o = __shfl_up(f, 32, 64); if (lane >= 32) f = fmaf(WP5, o, f); }
    return f;
}

#define PIN4(v) asm volatile("" : "+v"((v).x), "+v"((v).y), "+v"((v).z), "+v"((v).w))

struct ChunkBuf { float4 wf[NSB]; float4 af[NSB]; };

__device__ __forceinline__ void load_chunk(const float* __restrict__ wrow,
                                           const float* __restrict__ arow,
                                           int c0, int tid, ChunkBuf& b)
{
    #pragma unroll
    for (int i = 0; i < NSB; ++i) {
        int g = c0 + i * 1024 + 4 * tid;
        if (g < TLEN) {
            b.wf[i] = *reinterpret_cast<const float4*>(wrow + g);   // TLEN%4==0
            b.af[i] = *reinterpret_cast<const float4*>(arow + g);
        } else {
            b.wf[i] = make_float4(0.f, 0.f, 0.f, 0.f);
            b.af[i] = make_float4(0.f, 0.f, 0.f, 0.f);
        }
    }
    #pragma unroll
    for (int i = 0; i < NSB; ++i) { PIN4(b.wf[i]); PIN4(b.af[i]); }
}

// USE_ATOMIC=1 is the fallback path (ws too small): atomicMax into gmax.
template <int USE_ATOMIC>
__global__ __launch_bounds__(NT, 2)
void pink_mix_kernel(const float* __restrict__ waveform,
                     const float* __restrict__ white,
                     float* __restrict__ out,
                     unsigned int* __restrict__ gmax,
                     float* __restrict__ blockmax)
{
    __shared__ float sB[NSB + 1][4];   // wave totals: 8 superblocks + warm-up
    __shared__ float sM[4];            // per-wave max
    __shared__ float sW0;              // first white sample (global chunk 0 only)

    const int bx    = blockIdx.x;          // 0..BPC-1
    const int ch    = blockIdx.y;
    const int cbase = bx * CPB * CL;       // first sample of this block's span
    const size_t rowoff = (size_t)ch * TLEN;
    const float* __restrict__ wrow = white + rowoff;
    const float* __restrict__ arow = waveform + rowoff;
    float* __restrict__ orow = out + rowoff;

    const int tid  = threadIdx.x;
    const int lane = tid & 63;
    const int wv   = tid >> 6;

    // per-thread decay factors
    const float D4L = __builtin_exp2f((float)lane * L2A4);   // 0.99^(4*lane)
    const float DW  = __builtin_exp2f((float)wv   * L2A256); // 0.99^(256*wv)

    // ---- prologue: load chunk 0 into buffer A; warm-up float4 if needed ----
    ChunkBuf bA, bB;
    load_chunk(wrow, arow, cbase, tid, bA);
    float4 wu = make_float4(0.f, 0.f, 0.f, 0.f);
    if (bx > 0) {
        wu = *reinterpret_cast<const float4*>(wrow + (cbase - 1024) + 4 * tid);
        PIN4(wu);
    }

    float E  = 0.f;    // AR(1) state entering current chunk (block-uniform)
    float mx = 0.f;

    #pragma unroll
    for (int j = 0; j < CPB; ++j) {
        const int c0 = cbase + j * CL;
        ChunkBuf& cur = (j & 1) ? bB : bA;
        ChunkBuf& nxt = (j & 1) ? bA : bB;

        // ---- issue NEXT chunk's loads before computing current ----
        if (j + 1 < CPB)
            load_chunk(wrow, arow, c0 + CL, tid, nxt);

        // ---- scan phase on cur: per-superblock serial4 + wave scan ----
        float eB[NSB];
        #pragma unroll
        for (int i = 0; i < NSB; ++i) {
            float f = BC * cur.wf[i].x;
            f = fmaf(AC, f, BC * cur.wf[i].y);
            f = fmaf(AC, f, BC * cur.wf[i].z);
            f = fmaf(AC, f, BC * cur.wf[i].w);
            float pB = wave_scan4(f, lane);
            float e  = __shfl_up(pB, 1, 64);
            eB[i] = (lane == 0) ? 0.f : e;
            if (lane == 63) sB[i][wv] = pB;
        }
        if (j == 0) {
            if (bx > 0) {   // warm-up superblock -> sB[NSB]
                float f = BC * wu.x;
                f = fmaf(AC, f, BC * wu.y);
                f = fmaf(AC, f, BC * wu.z);
                f = fmaf(AC, f, BC * wu.w);
                float pB = wave_scan4(f, lane);
                if (lane == 63) sB[NSB][wv] = pB;
            }
            if (bx == 0 && tid == 0) sW0 = cur.wf[0].x;
        }
        __syncthreads();

        // ---- entry state for this block's first chunk ----
        if (j == 0) {
            if (bx > 0) {
                float t = sB[NSB][0];
                t = fmaf(A256, t, sB[NSB][1]);
                t = fmaf(A256, t, sB[NSB][2]);
                t = fmaf(A256, t, sB[NSB][3]);
                E = t;
            } else {
                E = sW0;    // chunk 0: E = w[0]; exact since a+b=1
            }
        }

        // ---- epilogue: per-superblock entry, rescan, fused mix+store+max ----
        #pragma unroll
        for (int i = 0; i < NSB; ++i) {
            const float b0 = sB[i][0], b1 = sB[i][1], b2 = sB[i][2];
            float wB = 0.f;                      // wave-exclusive prefix
            if (wv > 0) wB = b0;
            if (wv > 1) wB = fmaf(A256, wB, b1);
            if (wv > 2) wB = fmaf(A256, wB, b2);
            float f = fmaf(D4L, fmaf(DW, E, wB), eB[i]);

            int g = c0 + i * 1024 + 4 * tid;
            if (g < TLEN) {
                float4 m;
                f = fmaf(AC, f, BC * cur.wf[i].x); m.x = fmaf(NL, f, cur.af[i].x);
                f = fmaf(AC, f, BC * cur.wf[i].y); m.y = fmaf(NL, f, cur.af[i].y);
                f = fmaf(AC, f, BC * cur.wf[i].z); m.z = fmaf(NL, f, cur.af[i].z);
                f = fmaf(AC, f, BC * cur.wf[i].w); m.w = fmaf(NL, f, cur.af[i].w);
                *reinterpret_cast<float4*>(orow + g) = m;
                mx = fmaxf(mx, fmaxf(fmaxf(fabsf(m.x), fabsf(m.y)),
                                     fmaxf(fabsf(m.z), fabsf(m.w))));
            }
            // advance: E' = 0.99^1024 * E + T_i  (block-uniform)
            float t = b0;
            t = fmaf(A256, t, b1);
            t = fmaf(A256, t, b2);
            t = fmaf(A256, t, sB[i][3]);
            E = fmaf(A1024, E, t);
        }
        __syncthreads();    // protect sB reuse by next chunk's scan
    }

    // ---- block max: plain store (no hot atomic) ----
    #pragma unroll
    for (int d = 32; d >= 1; d >>= 1)
        mx = fmaxf(mx, __shfl_xor(mx, d, 64));
    if (lane == 0) sM[wv] = mx;
    __syncthreads();
    if (tid == 0) {
        float m = fmaxf(fmaxf(sM[0], sM[1]), fmaxf(sM[2], sM[3]));
        if (USE_ATOMIC) {
            atomicMax(gmax, __float_as_uint(m));
        } else {
            blockmax[ch * BPC + bx] = m;
        }
    }
}

// single-block reduce: NBLK per-block maxima -> gmax (uint float-bits)
__global__ __launch_bounds__(256)
void reduce_max_kernel(const float* __restrict__ blockmax, unsigned int* __restrict__ gmax)
{
    __shared__ float sM[4];
    const int tid  = threadIdx.x;
    const int lane = tid & 63;
    const int wv   = tid >> 6;
    float mx = 0.f;
    for (int i = tid; i < NBLK; i += 256)
        mx = fmaxf(mx, blockmax[i]);
    #pragma unroll
    for (int d = 32; d >= 1; d >>= 1)
        mx = fmaxf(mx, __shfl_xor(mx, d, 64));
    if (lane == 0) sM[wv] = mx;
    __syncthreads();
    if (tid == 0)
        *gmax = __float_as_uint(fmaxf(fmaxf(sM[0], sM[1]), fmaxf(sM[2], sM[3])));
}

__global__ __launch_bounds__(256)
void scale_kernel(float* __restrict__ out, const unsigned int* __restrict__ gmax, int n4)
{
    const float m = __uint_as_float(*gmax);
    const float s = (m > 1.0f) ? (1.0f / m) : 1.0f;
    float4* p = reinterpret_cast<float4*>(out);
    int i = blockIdx.x * blockDim.x + threadIdx.x;
    const int stride = gridDim.x * blockDim.x;
    for (; i < n4; i += stride) {
        float4 v = p[i];
        v.x *= s; v.y *= s; v.z *= s; v.w *= s;
        p[i] = v;
    }
}

extern "C" void kernel_launch(void* const* d_in, const int* in_sizes, int n_in,
                              void* d_out, int out_size, void* d_ws, size_t ws_size,
                              hipStream_t stream)
{
    const float* waveform = (const float*)d_in[0];
    const float* white    = (const float*)d_in[1];
    float* out            = (float*)d_out;

    // ws layout: [0] uint gmax (256B reserved), then NBLK floats of block maxima
    unsigned int* gmax = (unsigned int*)d_ws;
    float* blockmax    = (float*)((char*)d_ws + 256);
    const bool ws_ok   = ws_size >= 256 + (size_t)NBLK * sizeof(float);

    dim3 grid(BPC, CHANNELS);              // 3 x 256 = 768 persistent blocks
    const int n4 = out_size / 4;           // 14,112,000 float4s

    if (ws_ok) {
        hipLaunchKernelGGL((pink_mix_kernel<0>), grid, dim3(NT), 0, stream,
                           waveform, white, out, gmax, blockmax);
        hipLaunchKernelGGL(reduce_max_kernel, dim3(1), dim3(256), 0, stream,
                           blockmax, gmax);
    } else {
        hipLaunchKernelGGL(init_max_kernel, dim3(1), dim3(1), 0, stream, gmax);
        hipLaunchKernelGGL((pink_mix_kernel<1>), grid, dim3(NT), 0, stream,
                           waveform, white, out, gmax, blockmax);
    }
    hipLaunchKernelGGL(scale_kernel, dim3(3072), dim3(256), 0, stream,
                       out, gmax, n4);
}

// Round 8
// 273.982 us; speedup vs baseline: 1.0247x; 1.0247x over previous
//
#include <hip/hip_runtime.h>

// EnvironmentalAugmentations: pink = AR(1) scan of white noise (a=0.99, b=0.01),
// mixed = waveform + 0.05*pink, out = mixed / max(|mixed|) if max > 1 else mixed.
// Shapes: (256 channels, 220500 samples), f32 in / f32 out.
//
// R1-R7 learned: intra-block latency tricks don't move the 170 us / 2.7 TB/s
// floor; occupancy 40->60% didn't either. Loads are serialized behind dependent
// shuffle chains + barriers + the sequential superblock E-chain. R8 removes ALL
// dependencies between memory consumers:
//   K_A: wave-per-256-segment geometric totals (pure streaming read, no deps)
//   K_B: per-channel chain of totals -> exact entry state E per segment (tiny)
//   K_C: wave-per-segment apply (white+waveform+E -> out, max), no barriers,
//        no chains; white is LLC-warm from K_A.

#define TLEN 220500
#define CHANNELS 256

constexpr int SEGL = 256;                         // samples per segment (1 wave)
constexpr int SPC  = (TLEN + SEGL - 1) / SEGL;    // 862 segments per channel
constexpr int NSEG = SPC * CHANNELS;              // 220672 segments
constexpr int KB   = 14;                          // segs per lane in K_B (14*64>=862)
constexpr int GB   = 2048;                        // streaming grid blocks
constexpr int NBLK = GB;                          // blockmax entries (K_C)

constexpr float AC = 0.99f;
constexpr float BC = 0.01f;
constexpr float NL = 0.05f;

constexpr double dpow(double a, long n) { double r = 1.0; for (long i = 0; i < n; ++i) r *= a; return r; }

// wave scan multipliers at 4-sample granularity: 0.99^(4d)
constexpr float WP0 = (float)dpow(0.99, 4 * 1);
constexpr float WP1 = (float)dpow(0.99, 4 * 2);
constexpr float WP2 = (float)dpow(0.99, 4 * 4);
constexpr float WP3 = (float)dpow(0.99, 4 * 8);
constexpr float WP4 = (float)dpow(0.99, 4 * 16);
constexpr float WP5 = (float)dpow(0.99, 4 * 32);
constexpr float A256 = (float)dpow(0.99, 256);    // segment decay
// K_B lane-composition multipliers: (0.99^(256*14))^d ; d>=4 underflow to 0 (exact enough)
constexpr float CH1 = (float)dpow(0.99, 3584);    // ~2.3e-16
constexpr float CH2 = (float)dpow(0.99, 7168);    // ~5e-32
constexpr float L2A4   = -0.05799827878044602f;   // 4   * log2(0.99)
constexpr float L2A256 = -3.7118898419485456f;    // 256 * log2(0.99)

__device__ __forceinline__ float wave_scan4(float f, int lane) {
    { float o = __shfl_up(f, 1,  64); if (lane >= 1)  f = fmaf(WP0, o, f); }
    { float o = __shfl_up(f, 2,  64); if (lane >= 2)  f = fmaf(WP1, o, f); }
    { float o = __shfl_up(f, 4,  64); if (lane >= 4)  f = fmaf(WP2, o, f); }
    { float o = __shfl_up(f, 8,  64); if (lane >= 8)  f = fmaf(WP3, o, f); }
    { float o = __shfl_up(f, 16, 64); if (lane >= 16) f = fmaf(WP4, o, f); }
    { float o = __shfl_up(f, 32, 64); if (lane >= 32) f = fmaf(WP5, o, f); }
    return f;
}

// ---- K_A: per-segment geometric totals. One wave per 256-sample segment. ----
__global__ __launch_bounds__(256)
void totals_kernel(const float* __restrict__ white, float* __restrict__ totals)
{
    const int lane = threadIdx.x & 63;
    const int wv   = threadIdx.x >> 6;
    const int step = gridDim.x * 4;
    for (int S = blockIdx.x * 4 + wv; S < NSEG; S += step) {
        const unsigned ch = (unsigned)S / (unsigned)SPC;
        const unsigned s  = (unsigned)S - ch * SPC;
        const int off = (int)(s * SEGL) + 4 * lane;
        float4 v = make_float4(0.f, 0.f, 0.f, 0.f);
        if (off < TLEN)
            v = *reinterpret_cast<const float4*>(white + (size_t)ch * TLEN + off);
        float f = BC * v.x;
        f = fmaf(AC, f, BC * v.y);
        f = fmaf(AC, f, BC * v.z);
        f = fmaf(AC, f, BC * v.w);
        float p = wave_scan4(f, lane);
        if (lane == 63) totals[S] = p;
    }
}

// ---- K_B: chain totals into exact entry states E[s] per channel. ----
// E[s] = state entering segment s = A256^s * w0 + sum_{j<s} A256^(s-1-j) T[j];
// E[0] = w0 (exact: a*w0 + b*w0 = w0 reproduces pink[0] = w0).
__global__ __launch_bounds__(64)
void chain_kernel(const float* __restrict__ white,
                  const float* __restrict__ totals,
                  float* __restrict__ Earr)
{
    const int ch   = blockIdx.x;
    const int lane = threadIdx.x;
    const float w0 = white[(size_t)ch * TLEN];

    float T[KB];
    const int sbase = lane * KB;
    #pragma unroll
    for (int k = 0; k < KB; ++k) {
        int s = sbase + k;
        T[k] = (s < SPC) ? totals[ch * SPC + s] : 0.f;
    }
    // lane-local inclusive total over KB segments
    float B = 0.f;
    #pragma unroll
    for (int k = 0; k < KB; ++k) B = fmaf(A256, B, T[k]);
    // lane scan; distance>=4 contributions underflow to 0 (true values ~1e-63)
    float p = B;
    { float o = __shfl_up(p, 1, 64); if (lane >= 1) p = fmaf(CH1, o, p); }
    { float o = __shfl_up(p, 2, 64); if (lane >= 2) p = fmaf(CH2, o, p); }
    float X = __shfl_up(p, 1, 64);           // exclusive prefix
    if (lane == 0) X = 0.f;
    // emit entry states for this lane's segments
    float st = X;
    #pragma unroll
    for (int k = 0; k < KB; ++k) {
        int s = sbase + k;
        if (s < SPC)
            Earr[ch * SPC + s] = fmaf(__builtin_exp2f((float)s * L2A256), w0, st);
        st = fmaf(A256, st, T[k]);
    }
}

// ---- K_C: apply. One wave per segment; no barriers, no cross-iter deps. ----
__global__ __launch_bounds__(256)
void apply_kernel(const float* __restrict__ waveform,
                  const float* __restrict__ white,
                  const float* __restrict__ Earr,
                  float* __restrict__ out,
                  float* __restrict__ blockmax)
{
    __shared__ float sM[4];
    const int lane = threadIdx.x & 63;
    const int wv   = threadIdx.x >> 6;
    const float D4L = __builtin_exp2f((float)lane * L2A4);   // 0.99^(4*lane)
    const int step = gridDim.x * 4;
    float mx = 0.f;
    for (int S = blockIdx.x * 4 + wv; S < NSEG; S += step) {
        const unsigned ch = (unsigned)S / (unsigned)SPC;
        const unsigned s  = (unsigned)S - ch * SPC;
        const int base = (int)((size_t)0) ;  // (kept simple; indices fit int)
        const int off = (int)(s * SEGL) + 4 * lane;
        const int rowoff = (int)(ch * (unsigned)TLEN);
        const bool ok = off < TLEN;
        float4 wv4 = make_float4(0.f, 0.f, 0.f, 0.f);
        float4 av4 = make_float4(0.f, 0.f, 0.f, 0.f);
        if (ok) {
            wv4 = *reinterpret_cast<const float4*>(white + rowoff + off);
            av4 = *reinterpret_cast<const float4*>(waveform + rowoff + off);
        }
        const float E = Earr[S];             // wave-uniform broadcast
        (void)base;
        float f = BC * wv4.x;
        f = fmaf(AC, f, BC * wv4.y);
        f = fmaf(AC, f, BC * wv4.z);
        f = fmaf(AC, f, BC * wv4.w);
        float p = wave_scan4(f, lane);
        float e = __shfl_up(p, 1, 64);
        if (lane == 0) e = 0.f;
        // entry state for this lane: A^(4*lane)*E + e
        f = fmaf(D4L, E, e);
        float4 m;
        f = fmaf(AC, f, BC * wv4.x); m.x = fmaf(NL, f, av4.x);
        f = fmaf(AC, f, BC * wv4.y); m.y = fmaf(NL, f, av4.y);
        f = fmaf(AC, f, BC * wv4.z); m.z = fmaf(NL, f, av4.z);
        f = fmaf(AC, f, BC * wv4.w); m.w = fmaf(NL, f, av4.w);
        if (ok) {
            *reinterpret_cast<float4*>(out + rowoff + off) = m;
            mx = fmaxf(mx, fmaxf(fmaxf(fabsf(m.x), fabsf(m.y)),
                                 fmaxf(fabsf(m.z), fabsf(m.w))));
        }
    }
    #pragma unroll
    for (int d = 32; d >= 1; d >>= 1)
        mx = fmaxf(mx, __shfl_xor(mx, d, 64));
    if (lane == 0) sM[wv] = mx;
    __syncthreads();
    if (threadIdx.x == 0)
        blockmax[blockIdx.x] = fmaxf(fmaxf(sM[0], sM[1]), fmaxf(sM[2], sM[3]));
}

// ---- reduce NBLK block maxima -> gmax (float bits as uint) ----
__global__ __launch_bounds__(256)
void reduce_max_kernel(const float* __restrict__ blockmax, unsigned int* __restrict__ gmax)
{
    __shared__ float sM[4];
    const int tid  = threadIdx.x;
    const int lane = tid & 63;
    const int wv   = tid >> 6;
    float mx = 0.f;
    for (int i = tid; i < NBLK; i += 256)
        mx = fmaxf(mx, blockmax[i]);
    #pragma unroll
    for (int d = 32; d >= 1; d >>= 1)
        mx = fmaxf(mx, __shfl_xor(mx, d, 64));
    if (lane == 0) sM[wv] = mx;
    __syncthreads();
    if (tid == 0)
        *gmax = __float_as_uint(fmaxf(fmaxf(sM[0], sM[1]), fmaxf(sM[2], sM[3])));
}

__global__ __launch_bounds__(256)
void scale_kernel(float* __restrict__ out, const unsigned int* __restrict__ gmax, int n4)
{
    const float m = __uint_as_float(*gmax);
    const float s = (m > 1.0f) ? (1.0f / m) : 1.0f;
    float4* p = reinterpret_cast<float4*>(out);
    int i = blockIdx.x * blockDim.x + threadIdx.x;
    const int stride = gridDim.x * blockDim.x;
    for (; i < n4; i += stride) {
        float4 v = p[i];
        v.x *= s; v.y *= s; v.z *= s; v.w *= s;
        p[i] = v;
    }
}

// ---- fallback path (ws too small): R5-style fused kernel with atomicMax ----
__global__ void init_max_kernel(unsigned int* gmax) { *gmax = 0u; }

constexpr int FCL = 8192, FNT = 256, FNSB = 8;
constexpr int FNCHUNK = (TLEN + FCL - 1) / FCL;
constexpr float A1024 = (float)dpow(0.99, 1024);

__global__ __launch_bounds__(FNT, 4)
void pink_mix_fallback(const float* __restrict__ waveform,
                       const float* __restrict__ white,
                       float* __restrict__ out,
                       unsigned int* __restrict__ gmax)
{
    __shared__ float sB[FNSB + 1][4];
    __shared__ float sM[4];
    __shared__ float sW0;
    const int chunk = blockIdx.x, ch = blockIdx.y, c0 = chunk * FCL;
    const size_t rowoff = (size_t)ch * TLEN;
    const float* wrow = white + rowoff;
    const float* arow = waveform + rowoff;
    float* orow = out + rowoff;
    const int tid = threadIdx.x, lane = tid & 63, wvv = tid >> 6;
    float4 wf[FNSB], af[FNSB];
    #pragma unroll
    for (int i = 0; i < FNSB; ++i) {
        int g = c0 + i * 1024 + 4 * tid;
        if (g < TLEN) {
            wf[i] = *reinterpret_cast<const float4*>(wrow + g);
            af[i] = *reinterpret_cast<const float4*>(arow + g);
        } else { wf[i] = make_float4(0,0,0,0); af[i] = make_float4(0,0,0,0); }
    }
    float4 wu = make_float4(0,0,0,0);
    if (chunk > 0) wu = *reinterpret_cast<const float4*>(wrow + (c0 - 1024) + 4 * tid);
    float eB[FNSB];
    #pragma unroll
    for (int i = 0; i < FNSB; ++i) {
        float f = BC * wf[i].x;
        f = fmaf(AC, f, BC * wf[i].y); f = fmaf(AC, f, BC * wf[i].z); f = fmaf(AC, f, BC * wf[i].w);
        float pB = wave_scan4(f, lane);
        float e = __shfl_up(pB, 1, 64);
        eB[i] = (lane == 0) ? 0.f : e;
        if (lane == 63) sB[i][wvv] = pB;
    }
    if (chunk > 0) {
        float f = BC * wu.x;
        f = fmaf(AC, f, BC * wu.y); f = fmaf(AC, f, BC * wu.z); f = fmaf(AC, f, BC * wu.w);
        float pB = wave_scan4(f, lane);
        if (lane == 63) sB[FNSB][wvv] = pB;
    }
    if (tid == 0) sW0 = wf[0].x;
    __syncthreads();
    float E;
    if (chunk > 0) {
        float t = sB[FNSB][0];
        t = fmaf(A256, t, sB[FNSB][1]); t = fmaf(A256, t, sB[FNSB][2]); t = fmaf(A256, t, sB[FNSB][3]);
        E = t;
    } else E = sW0;
    const float D4L = __builtin_exp2f((float)lane * L2A4);
    const float DW  = __builtin_exp2f((float)wvv  * L2A256);
    float mx = 0.f;
    #pragma unroll
    for (int i = 0; i < FNSB; ++i) {
        const float b0 = sB[i][0], b1 = sB[i][1], b2 = sB[i][2];
        float wB = 0.f;
        if (wvv > 0) wB = b0;
        if (wvv > 1) wB = fmaf(A256, wB, b1);
        if (wvv > 2) wB = fmaf(A256, wB, b2);
        float f = fmaf(D4L, fmaf(DW, E, wB), eB[i]);
        int g = c0 + i * 1024 + 4 * tid;
        if (g < TLEN) {
            float4 m;
            f = fmaf(AC, f, BC * wf[i].x); m.x = fmaf(NL, f, af[i].x);
            f = fmaf(AC, f, BC * wf[i].y); m.y = fmaf(NL, f, af[i].y);
            f = fmaf(AC, f, BC * wf[i].z); m.z = fmaf(NL, f, af[i].z);
            f = fmaf(AC, f, BC * wf[i].w); m.w = fmaf(NL, f, af[i].w);
            *reinterpret_cast<float4*>(orow + g) = m;
            mx = fmaxf(mx, fmaxf(fmaxf(fabsf(m.x), fabsf(m.y)), fmaxf(fabsf(m.z), fabsf(m.w))));
        }
        float t = b0;
        t = fmaf(A256, t, b1); t = fmaf(A256, t, b2); t = fmaf(A256, t, sB[i][3]);
        E = fmaf(A1024, E, t);
    }
    #pragma unroll
    for (int d = 32; d >= 1; d >>= 1) mx = fmaxf(mx, __shfl_xor(mx, d, 64));
    if (lane == 0) sM[wvv] = mx;
    __syncthreads();
    if (tid == 0)
        atomicMax(gmax, __float_as_uint(fmaxf(fmaxf(sM[0], sM[1]), fmaxf(sM[2], sM[3]))));
}

extern "C" void kernel_launch(void* const* d_in, const int* in_sizes, int n_in,
                              void* d_out, int out_size, void* d_ws, size_t ws_size,
                              hipStream_t stream)
{
    const float* waveform = (const float*)d_in[0];
    const float* white    = (const float*)d_in[1];
    float* out            = (float*)d_out;

    // ws layout: gmax @0 (256B) | blockmax @256 (GB floats) | totals | Earr
    unsigned int* gmax = (unsigned int*)d_ws;
    float* blockmax = (float*)((char*)d_ws + 256);
    const size_t off_tot = 256 + (size_t)GB * 4;              // 8448
    float* totals = (float*)((char*)d_ws + ((off_tot + 255) & ~(size_t)255));
    float* Earr   = totals + NSEG;
    const size_t need = ((off_tot + 255) & ~(size_t)255) + 2 * (size_t)NSEG * 4;

    const int n4 = out_size / 4;

    if (ws_size >= need) {
        hipLaunchKernelGGL(totals_kernel, dim3(GB), dim3(256), 0, stream, white, totals);
        hipLaunchKernelGGL(chain_kernel, dim3(CHANNELS), dim3(64), 0, stream,
                           white, totals, Earr);
        hipLaunchKernelGGL(apply_kernel, dim3(GB), dim3(256), 0, stream,
                           waveform, white, Earr, out, blockmax);
        hipLaunchKernelGGL(reduce_max_kernel, dim3(1), dim3(256), 0, stream, blockmax, gmax);
    } else {
        hipLaunchKernelGGL(init_max_kernel, dim3(1), dim3(1), 0, stream, gmax);
        hipLaunchKernelGGL(pink_mix_fallback, dim3(FNCHUNK, CHANNELS), dim3(FNT), 0, stream,
                           waveform, white, out, gmax);
    }
    hipLaunchKernelGGL(scale_kernel, dim3(3072), dim3(256), 0, stream, out, gmax, n4);
}

// Round 9
// 255.234 us; speedup vs baseline: 1.0999x; 1.0735x over previous
//
#include <hip/hip_runtime.h>

// EnvironmentalAugmentations: pink = AR(1) scan of white noise (a=0.99, b=0.01),
// mixed = waveform + 0.05*pink, out = mixed / max(|mixed|) if max > 1 else mixed.
// Shapes: (256 channels, 220500 samples), f32 in / f32 out.
//
// R8 analysis: wave-independent streaming (apply_kernel) reached 5.2 TB/s
// aggregate fabric traffic; pipeline is traffic-bound (white read twice).
// R9: single fused kernel, per-WAVE chunks of 8192 samples + 1024 warm-up
// (0.99^1024 = 3.4e-5 -> truncation < 1e-6 in output). 16 passes of 512
// samples (8 per lane), 3-slot register pipeline (load p+2 before compute p,
// full unroll -> compile-time indices). No LDS data exchange, no barriers in
// the hot loop. Then tiny reduce + LLC-hot scale pass.

#define TLEN 220500
#define CHANNELS 256

constexpr int CHK  = 8192;               // samples per wave chunk
constexpr int PL   = 512;                // samples per pass (64 lanes x 8)
constexpr int NP   = CHK / PL;           // 16 main passes
constexpr int NCH  = 27;                 // chunks per channel
constexpr int NWAVES = NCH * CHANNELS;   // 6912 waves
constexpr int NB   = NWAVES / 4;         // 1728 blocks (4 waves each)

constexpr float AC = 0.99f;
constexpr float BC = 0.01f;
constexpr float NL = 0.05f;

constexpr double dpow(double a, long n) { double r = 1.0; for (long i = 0; i < n; ++i) r *= a; return r; }

// wave scan multipliers at 8-sample granularity: 0.99^(8d)
constexpr float S8P0 = (float)dpow(0.99, 8);
constexpr float S8P1 = (float)dpow(0.99, 16);
constexpr float S8P2 = (float)dpow(0.99, 32);
constexpr float S8P3 = (float)dpow(0.99, 64);
constexpr float S8P4 = (float)dpow(0.99, 128);
constexpr float S8P5 = (float)dpow(0.99, 256);
constexpr float A512 = (float)dpow(0.99, 512);     // pass decay
constexpr float L2A8 = -0.11599655756609923f;      // 8 * log2(0.99)

__device__ __forceinline__ float wave_scan8(float f, int lane) {
    { float o = __shfl_up(f, 1,  64); if (lane >= 1)  f = fmaf(S8P0, o, f); }
    { float o = __shfl_up(f, 2,  64); if (lane >= 2)  f = fmaf(S8P1, o, f); }
    { float o = __shfl_up(f, 4,  64); if (lane >= 4)  f = fmaf(S8P2, o, f); }
    { float o = __shfl_up(f, 8,  64); if (lane >= 8)  f = fmaf(S8P3, o, f); }
    { float o = __shfl_up(f, 16, 64); if (lane >= 16) f = fmaf(S8P4, o, f); }
    { float o = __shfl_up(f, 32, 64); if (lane >= 32) f = fmaf(S8P5, o, f); }
    return f;
}

__device__ __forceinline__ float serial8(const float4& a, const float4& b) {
    float f = BC * a.x;
    f = fmaf(AC, f, BC * a.y);
    f = fmaf(AC, f, BC * a.z);
    f = fmaf(AC, f, BC * a.w);
    f = fmaf(AC, f, BC * b.x);
    f = fmaf(AC, f, BC * b.y);
    f = fmaf(AC, f, BC * b.z);
    f = fmaf(AC, f, BC * b.w);
    return f;
}

__global__ void init_max_kernel(unsigned int* gmax) { *gmax = 0u; }

// USE_ATOMIC=1 is the fallback (ws too small): atomicMax into gmax.
template <int USE_ATOMIC>
__global__ __launch_bounds__(256)
void fused_kernel(const float* __restrict__ waveform,
                  const float* __restrict__ white,
                  float* __restrict__ out,
                  unsigned int* __restrict__ gmax,
                  float* __restrict__ blockmax)
{
    __shared__ float sM[4];
    const int tid  = threadIdx.x;
    const int lane = tid & 63;
    const int wv   = tid >> 6;
    const int W    = blockIdx.x * 4 + wv;          // global wave id
    const int ch   = W / NCH;
    const int chunk = W - ch * NCH;
    const size_t row = (size_t)ch * TLEN;
    const float* __restrict__ wrow = white + row;
    const float* __restrict__ arow = waveform + row;
    float* __restrict__ orow = out + row;
    const int c0 = chunk * CHK;
    const int l8 = 8 * lane;
    const float D8L = __builtin_exp2f((float)lane * L2A8);   // 0.99^(8*lane)

    // ---- issue warm-up loads (2 passes x 2 float4), always in-bounds ----
    float4 wu0, wu1, wu2, wu3;
    if (chunk > 0) {
        const float* wb = wrow + (c0 - 1024) + l8;
        wu0 = *reinterpret_cast<const float4*>(wb);
        wu1 = *reinterpret_cast<const float4*>(wb + 4);
        wu2 = *reinterpret_cast<const float4*>(wb + 512);
        wu3 = *reinterpret_cast<const float4*>(wb + 516);
    }

    // ---- 3-slot register pipeline over 16 passes of 512 samples ----
    float4 WA[3], WB[3], AA[3], AB[3];
    const float4 z4 = make_float4(0.f, 0.f, 0.f, 0.f);

    auto LDP = [&](int p, float4& wa, float4& wb, float4& aa, float4& ab) {
        const int g = c0 + p * PL + l8;
        wa = z4; wb = z4; aa = z4; ab = z4;
        if (g < TLEN) {                              // g%4==0, TLEN%4==0
            wa = *reinterpret_cast<const float4*>(wrow + g);
            aa = *reinterpret_cast<const float4*>(arow + g);
        }
        if (g + 4 < TLEN) {
            wb = *reinterpret_cast<const float4*>(wrow + g + 4);
            ab = *reinterpret_cast<const float4*>(arow + g + 4);
        }
    };

    LDP(0, WA[0], WB[0], AA[0], AB[0]);
    LDP(1, WA[1], WB[1], AA[1], AB[1]);

    // ---- entry state: warm-up total, or w[0] for chunk 0 (a*w0+b*w0 = w0) ----
    float E = 0.f;
    if (chunk > 0) {
        float f = serial8(wu0, wu1);
        float p = wave_scan8(f, lane);
        E = __shfl(p, 63, 64);
        f = serial8(wu2, wu3);
        p = wave_scan8(f, lane);
        E = fmaf(A512, E, __shfl(p, 63, 64));
    } else {
        E = __shfl(WA[0].x, 0, 64);
    }

    float mx = 0.f;
    #pragma unroll
    for (int p = 0; p < NP; ++p) {
        const int s  = p % 3;
        const int s2 = (p + 2) % 3;
        if (p + 2 < NP)
            LDP(p + 2, WA[s2], WB[s2], AA[s2], AB[s2]);   // issue before compute

        float f  = serial8(WA[s], WB[s]);
        float pb = wave_scan8(f, lane);
        float e  = __shfl_up(pb, 1, 64);
        if (lane == 0) e = 0.f;
        const float T = __shfl(pb, 63, 64);

        float fst = fmaf(D8L, E, e);                       // lane entry state
        float4 ma, mb;
        fst = fmaf(AC, fst, BC * WA[s].x); ma.x = fmaf(NL, fst, AA[s].x);
        fst = fmaf(AC, fst, BC * WA[s].y); ma.y = fmaf(NL, fst, AA[s].y);
        fst = fmaf(AC, fst, BC * WA[s].z); ma.z = fmaf(NL, fst, AA[s].z);
        fst = fmaf(AC, fst, BC * WA[s].w); ma.w = fmaf(NL, fst, AA[s].w);
        fst = fmaf(AC, fst, BC * WB[s].x); mb.x = fmaf(NL, fst, AB[s].x);
        fst = fmaf(AC, fst, BC * WB[s].y); mb.y = fmaf(NL, fst, AB[s].y);
        fst = fmaf(AC, fst, BC * WB[s].z); mb.z = fmaf(NL, fst, AB[s].z);
        fst = fmaf(AC, fst, BC * WB[s].w); mb.w = fmaf(NL, fst, AB[s].w);

        const int g = c0 + p * PL + l8;
        if (g < TLEN) {
            *reinterpret_cast<float4*>(orow + g) = ma;
            mx = fmaxf(mx, fmaxf(fmaxf(fabsf(ma.x), fabsf(ma.y)),
                                 fmaxf(fabsf(ma.z), fabsf(ma.w))));
        }
        if (g + 4 < TLEN) {
            *reinterpret_cast<float4*>(orow + g + 4) = mb;
            mx = fmaxf(mx, fmaxf(fmaxf(fabsf(mb.x), fabsf(mb.y)),
                                 fmaxf(fabsf(mb.z), fabsf(mb.w))));
        }
        E = fmaf(A512, E, T);                              // advance pass state
    }

    // ---- block max ----
    #pragma unroll
    for (int d = 32; d >= 1; d >>= 1)
        mx = fmaxf(mx, __shfl_xor(mx, d, 64));
    if (lane == 0) sM[wv] = mx;
    __syncthreads();
    if (tid == 0) {
        float m = fmaxf(fmaxf(sM[0], sM[1]), fmaxf(sM[2], sM[3]));
        if (USE_ATOMIC) {
            atomicMax(gmax, __float_as_uint(m));   // values >= 0
        } else {
            blockmax[blockIdx.x] = m;
        }
    }
}

// reduce NB block maxima -> gmax (float bits as uint)
__global__ __launch_bounds__(256)
void reduce_max_kernel(const float* __restrict__ blockmax, unsigned int* __restrict__ gmax)
{
    __shared__ float sM[4];
    const int tid  = threadIdx.x;
    const int lane = tid & 63;
    const int wv   = tid >> 6;
    float mx = 0.f;
    for (int i = tid; i < NB; i += 256)
        mx = fmaxf(mx, blockmax[i]);
    #pragma unroll
    for (int d = 32; d >= 1; d >>= 1)
        mx = fmaxf(mx, __shfl_xor(mx, d, 64));
    if (lane == 0) sM[wv] = mx;
    __syncthreads();
    if (tid == 0)
        *gmax = __float_as_uint(fmaxf(fmaxf(sM[0], sM[1]), fmaxf(sM[2], sM[3])));
}

__global__ __launch_bounds__(256)
void scale_kernel(float* __restrict__ out, const unsigned int* __restrict__ gmax, int n4)
{
    const float m = __uint_as_float(*gmax);
    const float s = (m > 1.0f) ? (1.0f / m) : 1.0f;
    float4* p = reinterpret_cast<float4*>(out);
    int i = blockIdx.x * blockDim.x + threadIdx.x;
    const int stride = gridDim.x * blockDim.x;
    for (; i < n4; i += stride) {
        float4 v = p[i];
        v.x *= s; v.y *= s; v.z *= s; v.w *= s;
        p[i] = v;
    }
}

extern "C" void kernel_launch(void* const* d_in, const int* in_sizes, int n_in,
                              void* d_out, int out_size, void* d_ws, size_t ws_size,
                              hipStream_t stream)
{
    const float* waveform = (const float*)d_in[0];
    const float* white    = (const float*)d_in[1];
    float* out            = (float*)d_out;

    // ws layout: gmax @0 (256B reserved) | blockmax @256 (NB floats)
    unsigned int* gmax = (unsigned int*)d_ws;
    float* blockmax    = (float*)((char*)d_ws + 256);
    const bool ws_ok   = ws_size >= 256 + (size_t)NB * sizeof(float);

    const int n4 = out_size / 4;           // 14,112,000 float4s

    if (ws_ok) {
        hipLaunchKernelGGL((fused_kernel<0>), dim3(NB), dim3(256), 0, stream,
                           waveform, white, out, gmax, blockmax);
        hipLaunchKernelGGL(reduce_max_kernel, dim3(1), dim3(256), 0, stream,
                           blockmax, gmax);
    } else {
        hipLaunchKernelGGL(init_max_kernel, dim3(1), dim3(1), 0, stream, gmax);
        hipLaunchKernelGGL((fused_kernel<1>), dim3(NB), dim3(256), 0, stream,
                           waveform, white, out, gmax, blockmax);
    }
    hipLaunchKernelGGL(scale_kernel, dim3(3072), dim3(256), 0, stream,
                       out, gmax, n4);
}